// Round 5
// baseline (1001.244 us; speedup 1.0000x reference)
//
#include <hip/hip_runtime.h>
#include <hip/hip_bf16.h>

#define TOKENS 4096
#define DDIM 1024
#define HDIM 2048
#define NEXP 8
#define NASSIGN 8192
#define TILE_M 256
#define MAX_TILES 80

typedef __attribute__((ext_vector_type(8))) __bf16 bf16x8;
typedef __attribute__((ext_vector_type(4))) float f32x4;
typedef __attribute__((ext_vector_type(4))) unsigned short u16x4;

__device__ __forceinline__ unsigned short f2bf(float f) {
    unsigned int u = __builtin_bit_cast(unsigned int, f);
    u += 0x7fffu + ((u >> 16) & 1u);
    return (unsigned short)(u >> 16);
}

// ---------------- router: logits = x @ Wr + br, top-2 + softmax; also x->bf16 ----------------
__global__ __launch_bounds__(256) void router_kernel(
    const float* __restrict__ x, const float* __restrict__ Wr, const float* __restrict__ br,
    unsigned short* __restrict__ x_bf, int* __restrict__ topk_e, float* __restrict__ topk_s)
{
    const int t = blockIdx.x * 4 + (threadIdx.x >> 6);
    const int lane = threadIdx.x & 63;
    const float* xr = x + (long)t * DDIM;
    unsigned short* xo = x_bf + (long)t * DDIM;
    float acc[8] = {0.f,0.f,0.f,0.f,0.f,0.f,0.f,0.f};
    for (int it = 0; it < DDIM / 64; ++it) {
        const int d = it * 64 + lane;
        const float xv = xr[d];
        xo[d] = f2bf(xv);
        const float4 w0 = *(const float4*)(Wr + d * 8);
        const float4 w1 = *(const float4*)(Wr + d * 8 + 4);
        acc[0] += xv * w0.x; acc[1] += xv * w0.y; acc[2] += xv * w0.z; acc[3] += xv * w0.w;
        acc[4] += xv * w1.x; acc[5] += xv * w1.y; acc[6] += xv * w1.z; acc[7] += xv * w1.w;
    }
#pragma unroll
    for (int e = 0; e < 8; ++e) {
        float v = acc[e];
        for (int off = 32; off > 0; off >>= 1) v += __shfl_down(v, off, 64);
        acc[e] = v;
    }
    if (lane == 0) {
        float lg[8];
#pragma unroll
        for (int e = 0; e < 8; ++e) lg[e] = acc[e] + br[e];
        int i0 = 0; float v0 = lg[0];
#pragma unroll
        for (int e = 1; e < 8; ++e) if (lg[e] > v0) { v0 = lg[e]; i0 = e; }
        int i1 = -1; float v1 = -3.4e38f;
#pragma unroll
        for (int e = 0; e < 8; ++e) if (e != i0 && lg[e] > v1) { v1 = lg[e]; i1 = e; }
        const float e1 = expf(v1 - v0);
        const float inv = 1.f / (1.f + e1);
        topk_e[t * 2]     = i0; topk_s[t * 2]     = inv;
        topk_e[t * 2 + 1] = i1; topk_s[t * 2 + 1] = e1 * inv;
    }
}

// ---------------- bucketing: counts -> scan -> scatter + tile map (256-row tiles) ----------------
__global__ __launch_bounds__(1024) void build_lists_kernel(
    const int* __restrict__ topk_e, const float* __restrict__ topk_s,
    int* __restrict__ token_list, float* __restrict__ score_list, int* __restrict__ meta)
{
    __shared__ int cnt[NEXP];
    __shared__ int base[NEXP];
    __shared__ int cur[NEXP];
    const int tid = threadIdx.x;
    if (tid < NEXP) cnt[tid] = 0;
    __syncthreads();
    for (int i = tid; i < NASSIGN; i += 1024) atomicAdd(&cnt[topk_e[i]], 1);
    __syncthreads();
    if (tid == 0) {
        int accu = 0;
        for (int e = 0; e < NEXP; ++e) { base[e] = accu; cur[e] = accu; accu += cnt[e]; }
        int ntile = 0;
        for (int e = 0; e < NEXP; ++e) {
            const int c = cnt[e];
            for (int r = 0; r * TILE_M < c; ++r) {
                meta[1 + ntile] = e;
                meta[1 + MAX_TILES + ntile] = base[e] + r * TILE_M;
                meta[1 + 2 * MAX_TILES + ntile] = (c - r * TILE_M) < TILE_M ? (c - r * TILE_M) : TILE_M;
                ++ntile;
            }
        }
        meta[0] = ntile;
    }
    __syncthreads();
    for (int i = tid; i < NASSIGN; i += 1024) {
        const int e = topk_e[i];
        const int slot = atomicAdd(&cur[e], 1);
        token_list[slot] = i >> 1;
        score_list[slot] = topk_s[i];
    }
}

// ---------------- W1 [E][D][H] + W2 [E][H][D] fp32 -> [E][N][K] bf16, one launch ----------------
// (No memoization: rounds 2/3 died in-container from touching memory past
// meta[240] — workspace is sized to the original layout. Do NOT exceed it.)
__global__ __launch_bounds__(256) void transpose_cvt_kernel(
    const float* __restrict__ W1, const float* __restrict__ W2,
    unsigned short* __restrict__ W1t, unsigned short* __restrict__ W2t)
{
    __shared__ unsigned short tile[64 * 68];
    const int z = blockIdx.y;           // 0..7 -> W1 experts, 8..15 -> W2 experts
    const bool is1 = z < 8;
    const int e = is1 ? z : z - 8;
    const int K = is1 ? DDIM : HDIM;
    const int N = is1 ? HDIM : DDIM;
    const float* src = (is1 ? W1 : W2) + (long)e * K * N;
    unsigned short* dst = (is1 ? W1t : W2t) + (long)e * K * N;
    const int ktiles = K >> 6;
    const int k0 = (blockIdx.x % ktiles) * 64;
    const int n0 = (blockIdx.x / ktiles) * 64;
    const int r0 = threadIdx.x >> 4;
    const int c4 = (threadIdx.x & 15) * 4;
#pragma unroll
    for (int i = 0; i < 4; ++i) {
        const int r = r0 + i * 16;       // k-row within tile
        const float4 v = *(const float4*)(src + (long)(k0 + r) * N + n0 + c4);
        tile[(c4 + 0) * 68 + r] = f2bf(v.x);
        tile[(c4 + 1) * 68 + r] = f2bf(v.y);
        tile[(c4 + 2) * 68 + r] = f2bf(v.z);
        tile[(c4 + 3) * 68 + r] = f2bf(v.w);
    }
    __syncthreads();
#pragma unroll
    for (int i = 0; i < 4; ++i) {
        const int rn = r0 + i * 16;      // n-row within tile
        u16x4 o;
        o.x = tile[rn * 68 + c4 + 0];
        o.y = tile[rn * 68 + c4 + 1];
        o.z = tile[rn * 68 + c4 + 2];
        o.w = tile[rn * 68 + c4 + 3];
        *(u16x4*)(dst + (long)(n0 + rn) * K + k0 + c4) = o;
    }
}

// ---------------- grouped expert GEMM: 256x256 tile, BK=64, 8 waves, SINGLE-buffer ----------------
// Round 5: round 4's 128KB dbuf forced 1 block/CU -> 264 active blocks on 256
// CUs ran as 256 + 8-straggler SEQUENTIAL sweeps (dispatch ~= 2x block time;
// Occupancy 13.8% ~= half of the 25% steady-state proves the idle tail), and
// killed the cross-block stage/compute overlap that round 0 relied on.
// Fix: keep the 256^2 tile (halves total staging bytes vs 128^2: 270 MB vs
// 655 MB, and staging throughput is the measured limiter) but go back to the
// round-0 SINGLE-buffer schedule -> 64 KB LDS -> 2 blocks/CU -> all 264 blocks
// co-resident (no tail) and paired blocks hide each other's stage latency.
// Same XOR-chunk LDS swizzle (row&7 == l15&7 holds at 256 rows).
// KDIM = full row stride of A/B; KLOC = per-block K extent (split-K via
// blockIdx.z for GEMM2 keeps >=264 blocks in flight; bias only at z==0).
template<int KDIM, int KLOC, int NDIM, bool G2>
__global__ __launch_bounds__(512, 4) void expert_gemm(
    const unsigned short* __restrict__ Abase,
    const unsigned short* __restrict__ Bt,
    const float* __restrict__ bias,
    unsigned short* __restrict__ Hout,
    float* __restrict__ Out,
    const int* __restrict__ token_list,
    const float* __restrict__ score_list,
    const int* __restrict__ meta)
{
    const int nt = meta[0];
    // XCD-aware BIJECTIVE partition over tiles (gridDim.x = 40, xcd = bx&7).
    // nt <= 39 always, so cnt_i <= 5 = gridDim.x/8; every tile covered once.
    const int xcd = blockIdx.x & 7;
    const int off = blockIdx.x >> 3;
    const int q = nt >> 3;
    const int r = nt & 7;
    const int cnt_i = q + (xcd < r ? 1 : 0);
    if (off >= cnt_i) return;
    const int t = xcd * q + (xcd < r ? xcd : r) + off;
    const int e = meta[1 + t];
    const int slot0 = meta[1 + MAX_TILES + t];
    const int rows_valid = meta[1 + 2 * MAX_TILES + t];
    const int n0 = blockIdx.y * 256;
    const int k_start = blockIdx.z * KLOC;

    __shared__ unsigned short As[256 * 64];   // 32 KB
    __shared__ unsigned short Bs[256 * 64];   // 32 KB -> 64 KB total, 2 blocks/CU

    const int tid = threadIdx.x;
    const int lane = tid & 63;
    const int w = tid >> 6;      // 8 waves: 2M x 4N
    const int wm = w >> 2;
    const int wn = w & 3;
    const int quad = lane >> 4;
    const int l15 = lane & 15;

    // Staging: 2048 16B-chunks per matrix per K-tile; chunk = c*512 + tid.
    // LDS slot for chunk = row*64 + (chunk&7)*8 shorts; global k-chunk there is
    // (chunk&7) XOR (row&7) -> bank-conflict-free ds_read_b128.
    const unsigned short* aptr[4];
    const unsigned short* bptr[4];
    int loff[4];
#pragma unroll
    for (int c = 0; c < 4; ++c) {
        const int chunk = c * 512 + tid;
        const int row = chunk >> 3;
        const int kc = (chunk & 7) ^ (row & 7);
        const int rr = row < rows_valid ? row : rows_valid - 1;
        const long arow = G2 ? (long)(slot0 + rr) : (long)token_list[slot0 + rr];
        aptr[c] = Abase + arow * (long)KDIM + k_start + kc * 8;
        bptr[c] = Bt + ((long)e * NDIM + n0 + row) * (long)KDIM + k_start + kc * 8;
        loff[c] = (c * 512 + w * 64) * 8;
    }

    f32x4 acc[8][4] = {};

#pragma unroll 1
    for (int k0 = 0; k0 < KLOC; k0 += 64) {
#pragma unroll
        for (int c = 0; c < 4; ++c) {
            __builtin_amdgcn_global_load_lds(
                (const __attribute__((address_space(1))) unsigned int*)aptr[c],
                (__attribute__((address_space(3))) unsigned int*)&As[loff[c]], 16, 0, 0);
            aptr[c] += 64;
        }
#pragma unroll
        for (int c = 0; c < 4; ++c) {
            __builtin_amdgcn_global_load_lds(
                (const __attribute__((address_space(1))) unsigned int*)bptr[c],
                (__attribute__((address_space(3))) unsigned int*)&Bs[loff[c]], 16, 0, 0);
            bptr[c] += 64;
        }
        __syncthreads();

#pragma unroll
        for (int h = 0; h < 2; ++h) {
            bf16x8 af[8], bfr[4];
#pragma unroll
            for (int mi = 0; mi < 8; ++mi)
                af[mi] = *(const bf16x8*)&As[(wm * 128 + mi * 16 + l15) * 64 + ((h * 4 + quad) ^ (l15 & 7)) * 8];
#pragma unroll
            for (int ni = 0; ni < 4; ++ni)
                bfr[ni] = *(const bf16x8*)&Bs[(wn * 64 + ni * 16 + l15) * 64 + ((h * 4 + quad) ^ (l15 & 7)) * 8];
#pragma unroll
            for (int mi = 0; mi < 8; ++mi)
#pragma unroll
                for (int ni = 0; ni < 4; ++ni)
                    acc[mi][ni] = __builtin_amdgcn_mfma_f32_16x16x32_bf16(af[mi], bfr[ni], acc[mi][ni], 0, 0, 0);
        }
        __syncthreads();
    }

#pragma unroll
    for (int mi = 0; mi < 8; ++mi) {
#pragma unroll
        for (int ni = 0; ni < 4; ++ni) {
            const int col = n0 + wn * 64 + ni * 16 + l15;
#pragma unroll
            for (int rr = 0; rr < 4; ++rr) {
                const int row = wm * 128 + mi * 16 + quad * 4 + rr;
                if (row < rows_valid) {
                    float v = acc[mi][ni][rr];
                    if (!G2 || blockIdx.z == 0) v += bias[e * NDIM + col];
                    if (!G2) {
                        v = v > 0.f ? v : 0.f;
                        Hout[(long)(slot0 + row) * NDIM + col] = f2bf(v);
                    } else {
                        const int slot = slot0 + row;
                        const int tok = token_list[slot];
                        const float s = score_list[slot];
                        unsafeAtomicAdd(&Out[(long)tok * NDIM + col], s * v);
                    }
                }
            }
        }
    }
}

extern "C" void kernel_launch(void* const* d_in, const int* in_sizes, int n_in,
                              void* d_out, int out_size, void* d_ws, size_t ws_size,
                              hipStream_t stream)
{
    (void)in_sizes; (void)n_in; (void)out_size; (void)ws_size;
    const float* x  = (const float*)d_in[0];
    const float* Wr = (const float*)d_in[1];
    const float* br = (const float*)d_in[2];
    const float* W1 = (const float*)d_in[3];
    const float* b1 = (const float*)d_in[4];
    const float* W2 = (const float*)d_in[5];
    const float* b2 = (const float*)d_in[6];
    float* out = (float*)d_out;

    char* ws = (char*)d_ws;
    unsigned short* x_bf  = (unsigned short*)(ws);                 // 8388608
    unsigned short* W1t   = (unsigned short*)(ws + 8388608);       // 33554432
    unsigned short* W2t   = (unsigned short*)(ws + 41943040);      // 33554432
    unsigned short* hbuf  = (unsigned short*)(ws + 75497472);      // 33554432
    int*   topk_e     = (int*)(ws + 109051904);
    float* topk_s     = (float*)(ws + 109084672);
    int*   token_list = (int*)(ws + 109117440);
    float* score_list = (float*)(ws + 109150208);
    int*   meta       = (int*)(ws + 109182976);   // meta[0..240] tiles; DO NOT touch past [240]

    hipMemsetAsync(d_out, 0, (size_t)TOKENS * DDIM * sizeof(float), stream);

    router_kernel<<<TOKENS / 4, 256, 0, stream>>>(x, Wr, br, x_bf, topk_e, topk_s);
    build_lists_kernel<<<1, 1024, 0, stream>>>(topk_e, topk_s, token_list, score_list, meta);
    transpose_cvt_kernel<<<dim3(512, 16), 256, 0, stream>>>(W1, W2, W1t, W2t);
    expert_gemm<DDIM, DDIM, HDIM, false><<<dim3(40, HDIM / 256, 1), 512, 0, stream>>>(
        x_bf, W1t, b1, hbuf, nullptr, token_list, score_list, meta);
    expert_gemm<HDIM, HDIM / 2, DDIM, true><<<dim3(40, DDIM / 256, 2), 512, 0, stream>>>(
        hbuf, W2t, b2, nullptr, out, token_list, score_list, meta);
}

// Round 6
// 409.229 us; speedup vs baseline: 2.4467x; 2.4467x over previous
//
#include <hip/hip_runtime.h>
#include <hip/hip_bf16.h>

#define TOKENS 4096
#define DDIM 1024
#define HDIM 2048
#define NEXP 8
#define NASSIGN 8192
#define TILE_M 256
#define MAX_TILES 80

typedef __attribute__((ext_vector_type(8))) __bf16 bf16x8;
typedef __attribute__((ext_vector_type(4))) float f32x4;
typedef __attribute__((ext_vector_type(4))) unsigned short u16x4;

__device__ __forceinline__ unsigned short f2bf(float f) {
    unsigned int u = __builtin_bit_cast(unsigned int, f);
    u += 0x7fffu + ((u >> 16) & 1u);
    return (unsigned short)(u >> 16);
}

// ---------------- router: logits = x @ Wr + br, top-2 + softmax; also x->bf16 ----------------
__global__ __launch_bounds__(256) void router_kernel(
    const float* __restrict__ x, const float* __restrict__ Wr, const float* __restrict__ br,
    unsigned short* __restrict__ x_bf, int* __restrict__ topk_e, float* __restrict__ topk_s)
{
    const int t = blockIdx.x * 4 + (threadIdx.x >> 6);
    const int lane = threadIdx.x & 63;
    const float* xr = x + (long)t * DDIM;
    unsigned short* xo = x_bf + (long)t * DDIM;
    float acc[8] = {0.f,0.f,0.f,0.f,0.f,0.f,0.f,0.f};
    for (int it = 0; it < DDIM / 64; ++it) {
        const int d = it * 64 + lane;
        const float xv = xr[d];
        xo[d] = f2bf(xv);
        const float4 w0 = *(const float4*)(Wr + d * 8);
        const float4 w1 = *(const float4*)(Wr + d * 8 + 4);
        acc[0] += xv * w0.x; acc[1] += xv * w0.y; acc[2] += xv * w0.z; acc[3] += xv * w0.w;
        acc[4] += xv * w1.x; acc[5] += xv * w1.y; acc[6] += xv * w1.z; acc[7] += xv * w1.w;
    }
#pragma unroll
    for (int e = 0; e < 8; ++e) {
        float v = acc[e];
        for (int off = 32; off > 0; off >>= 1) v += __shfl_down(v, off, 64);
        acc[e] = v;
    }
    if (lane == 0) {
        float lg[8];
#pragma unroll
        for (int e = 0; e < 8; ++e) lg[e] = acc[e] + br[e];
        int i0 = 0; float v0 = lg[0];
#pragma unroll
        for (int e = 1; e < 8; ++e) if (lg[e] > v0) { v0 = lg[e]; i0 = e; }
        int i1 = -1; float v1 = -3.4e38f;
#pragma unroll
        for (int e = 0; e < 8; ++e) if (e != i0 && lg[e] > v1) { v1 = lg[e]; i1 = e; }
        const float e1 = expf(v1 - v0);
        const float inv = 1.f / (1.f + e1);
        topk_e[t * 2]     = i0; topk_s[t * 2]     = inv;
        topk_e[t * 2 + 1] = i1; topk_s[t * 2 + 1] = e1 * inv;
    }
}

// ---------------- bucketing: counts -> scan -> scatter + tile map (256-row tiles) ----------------
__global__ __launch_bounds__(1024) void build_lists_kernel(
    const int* __restrict__ topk_e, const float* __restrict__ topk_s,
    int* __restrict__ token_list, float* __restrict__ score_list, int* __restrict__ meta)
{
    __shared__ int cnt[NEXP];
    __shared__ int base[NEXP];
    __shared__ int cur[NEXP];
    const int tid = threadIdx.x;
    if (tid < NEXP) cnt[tid] = 0;
    __syncthreads();
    for (int i = tid; i < NASSIGN; i += 1024) atomicAdd(&cnt[topk_e[i]], 1);
    __syncthreads();
    if (tid == 0) {
        int accu = 0;
        for (int e = 0; e < NEXP; ++e) { base[e] = accu; cur[e] = accu; accu += cnt[e]; }
        int ntile = 0;
        for (int e = 0; e < NEXP; ++e) {
            const int c = cnt[e];
            for (int r = 0; r * TILE_M < c; ++r) {
                meta[1 + ntile] = e;
                meta[1 + MAX_TILES + ntile] = base[e] + r * TILE_M;
                meta[1 + 2 * MAX_TILES + ntile] = (c - r * TILE_M) < TILE_M ? (c - r * TILE_M) : TILE_M;
                ++ntile;
            }
        }
        meta[0] = ntile;
    }
    __syncthreads();
    for (int i = tid; i < NASSIGN; i += 1024) {
        const int e = topk_e[i];
        const int slot = atomicAdd(&cur[e], 1);
        token_list[slot] = i >> 1;
        score_list[slot] = topk_s[i];
    }
}

// ---------------- W1 [E][D][H] + W2 [E][H][D] fp32 -> [E][N][K] bf16, one launch ----------------
// (No memoization: rounds 2/3 died from touching memory past meta[240] —
// workspace is sized to the original layout. Do NOT exceed it.)
__global__ __launch_bounds__(256) void transpose_cvt_kernel(
    const float* __restrict__ W1, const float* __restrict__ W2,
    unsigned short* __restrict__ W1t, unsigned short* __restrict__ W2t)
{
    __shared__ unsigned short tile[64 * 68];
    const int z = blockIdx.y;           // 0..7 -> W1 experts, 8..15 -> W2 experts
    const bool is1 = z < 8;
    const int e = is1 ? z : z - 8;
    const int K = is1 ? DDIM : HDIM;
    const int N = is1 ? HDIM : DDIM;
    const float* src = (is1 ? W1 : W2) + (long)e * K * N;
    unsigned short* dst = (is1 ? W1t : W2t) + (long)e * K * N;
    const int ktiles = K >> 6;
    const int k0 = (blockIdx.x % ktiles) * 64;
    const int n0 = (blockIdx.x / ktiles) * 64;
    const int r0 = threadIdx.x >> 4;
    const int c4 = (threadIdx.x & 15) * 4;
#pragma unroll
    for (int i = 0; i < 4; ++i) {
        const int r = r0 + i * 16;       // k-row within tile
        const float4 v = *(const float4*)(src + (long)(k0 + r) * N + n0 + c4);
        tile[(c4 + 0) * 68 + r] = f2bf(v.x);
        tile[(c4 + 1) * 68 + r] = f2bf(v.y);
        tile[(c4 + 2) * 68 + r] = f2bf(v.z);
        tile[(c4 + 3) * 68 + r] = f2bf(v.w);
    }
    __syncthreads();
#pragma unroll
    for (int i = 0; i < 4; ++i) {
        const int rn = r0 + i * 16;      // n-row within tile
        u16x4 o;
        o.x = tile[rn * 68 + c4 + 0];
        o.y = tile[rn * 68 + c4 + 1];
        o.z = tile[rn * 68 + c4 + 2];
        o.w = tile[rn * 68 + c4 + 3];
        *(u16x4*)(dst + (long)(n0 + rn) * K + k0 + c4) = o;
    }
}

// ---------------- grouped expert GEMM: 256x256 tile, BK=64, 16 waves, SINGLE-buffer ----------------
// Round 6. Model from rounds 0/4: GEMM time ~= staged_bytes / ~6 TB/s (L3-path
// staging ceiling; round 0: 553MB/89us, round 4 steady: 277MB/55us). So the
// 256^2 tile (halves staged bytes vs 128^2) is right — round 4's loss was the
// residency tail (128KB dbuf -> 1 block/CU -> 264 blocks = 2 sequential sweeps)
// and round 5's loss was forced-occupancy register spill (launch_bounds min=4
// with a 240-reg footprint -> 800MB scratch traffic).
// This round: 256^2, SINGLE-buffer (64KB LDS), 1024 threads = 16 waves (4x4
// wave grid, 64x64 output/wave, acc=64 regs/lane, ~144 unified regs/wave) ->
// 2 blocks/CU by both LDS (128<=160KB) and regs. 264-288 active blocks on 512
// resident slots: no tail, and paired blocks hide each other's stage latency
// (round-0-proven schedule: stage -> sync -> comp -> sync).
// Same XOR-chunk LDS swizzle (bank-conflict-free ds_read_b128, measured 0).
// KDIM = full row stride; KLOC = per-block K extent (split-K z for GEMM2;
// partial sums meet at the atomicAdd, bias only at z==0).
template<int KDIM, int KLOC, int NDIM, bool G2>
__global__ __launch_bounds__(1024, 4) void expert_gemm(
    const unsigned short* __restrict__ Abase,
    const unsigned short* __restrict__ Bt,
    const float* __restrict__ bias,
    unsigned short* __restrict__ Hout,
    float* __restrict__ Out,
    const int* __restrict__ token_list,
    const float* __restrict__ score_list,
    const int* __restrict__ meta)
{
    const int nt = meta[0];
    // XCD-aware BIJECTIVE partition over tiles (gridDim.x = 40, xcd = bx&7).
    // nt <= 39 always, so cnt_i <= 5 = gridDim.x/8; every tile covered once.
    const int xcd = blockIdx.x & 7;
    const int off = blockIdx.x >> 3;
    const int q = nt >> 3;
    const int r = nt & 7;
    const int cnt_i = q + (xcd < r ? 1 : 0);
    if (off >= cnt_i) return;
    const int t = xcd * q + (xcd < r ? xcd : r) + off;
    const int e = meta[1 + t];
    const int slot0 = meta[1 + MAX_TILES + t];
    const int rows_valid = meta[1 + 2 * MAX_TILES + t];
    const int n0 = blockIdx.y * 256;
    const int k_start = blockIdx.z * KLOC;

    __shared__ unsigned short As[256 * 64];   // 32 KB
    __shared__ unsigned short Bs[256 * 64];   // 32 KB -> 64 KB total, 2 blocks/CU

    const int tid = threadIdx.x;
    const int lane = tid & 63;
    const int w = tid >> 6;      // 16 waves: 4M x 4N, 64x64 output each
    const int wm = w >> 2;
    const int wn = w & 3;
    const int quad = lane >> 4;
    const int l15 = lane & 15;

    // Staging: 2048 16B-chunks per matrix per K-tile; chunk = c*1024 + tid (c<2).
    // LDS slot for chunk = row*64 + (chunk&7)*8 shorts; global k-chunk there is
    // (chunk&7) XOR (row&7) -> bank-conflict-free ds_read_b128.
    const unsigned short* aptr[2];
    const unsigned short* bptr[2];
    int loff[2];
#pragma unroll
    for (int c = 0; c < 2; ++c) {
        const int chunk = c * 1024 + tid;
        const int row = chunk >> 3;
        const int kc = (chunk & 7) ^ (row & 7);
        const int rr = row < rows_valid ? row : rows_valid - 1;
        const long arow = G2 ? (long)(slot0 + rr) : (long)token_list[slot0 + rr];
        aptr[c] = Abase + arow * (long)KDIM + k_start + kc * 8;
        bptr[c] = Bt + ((long)e * NDIM + n0 + row) * (long)KDIM + k_start + kc * 8;
        loff[c] = (c * 1024 + w * 64) * 8;   // wave-uniform base; HW adds lane*16B
    }

    f32x4 acc[4][4] = {};

#pragma unroll 1
    for (int k0 = 0; k0 < KLOC; k0 += 64) {
#pragma unroll
        for (int c = 0; c < 2; ++c) {
            __builtin_amdgcn_global_load_lds(
                (const __attribute__((address_space(1))) unsigned int*)aptr[c],
                (__attribute__((address_space(3))) unsigned int*)&As[loff[c]], 16, 0, 0);
            aptr[c] += 64;
        }
#pragma unroll
        for (int c = 0; c < 2; ++c) {
            __builtin_amdgcn_global_load_lds(
                (const __attribute__((address_space(1))) unsigned int*)bptr[c],
                (__attribute__((address_space(3))) unsigned int*)&Bs[loff[c]], 16, 0, 0);
            bptr[c] += 64;
        }
        __syncthreads();

#pragma unroll
        for (int h = 0; h < 2; ++h) {
            bf16x8 af[4], bfr[4];
#pragma unroll
            for (int mi = 0; mi < 4; ++mi)
                af[mi] = *(const bf16x8*)&As[(wm * 64 + mi * 16 + l15) * 64 + ((h * 4 + quad) ^ (l15 & 7)) * 8];
#pragma unroll
            for (int ni = 0; ni < 4; ++ni)
                bfr[ni] = *(const bf16x8*)&Bs[(wn * 64 + ni * 16 + l15) * 64 + ((h * 4 + quad) ^ (l15 & 7)) * 8];
#pragma unroll
            for (int mi = 0; mi < 4; ++mi)
#pragma unroll
                for (int ni = 0; ni < 4; ++ni)
                    acc[mi][ni] = __builtin_amdgcn_mfma_f32_16x16x32_bf16(af[mi], bfr[ni], acc[mi][ni], 0, 0, 0);
        }
        __syncthreads();
    }

#pragma unroll
    for (int mi = 0; mi < 4; ++mi) {
#pragma unroll
        for (int ni = 0; ni < 4; ++ni) {
            const int col = n0 + wn * 64 + ni * 16 + l15;
#pragma unroll
            for (int rr = 0; rr < 4; ++rr) {
                const int row = wm * 64 + mi * 16 + quad * 4 + rr;
                if (row < rows_valid) {
                    float v = acc[mi][ni][rr];
                    if (!G2 || blockIdx.z == 0) v += bias[e * NDIM + col];
                    if (!G2) {
                        v = v > 0.f ? v : 0.f;
                        Hout[(long)(slot0 + row) * NDIM + col] = f2bf(v);
                    } else {
                        const int slot = slot0 + row;
                        const int tok = token_list[slot];
                        const float s = score_list[slot];
                        unsafeAtomicAdd(&Out[(long)tok * NDIM + col], s * v);
                    }
                }
            }
        }
    }
}

extern "C" void kernel_launch(void* const* d_in, const int* in_sizes, int n_in,
                              void* d_out, int out_size, void* d_ws, size_t ws_size,
                              hipStream_t stream)
{
    (void)in_sizes; (void)n_in; (void)out_size; (void)ws_size;
    const float* x  = (const float*)d_in[0];
    const float* Wr = (const float*)d_in[1];
    const float* br = (const float*)d_in[2];
    const float* W1 = (const float*)d_in[3];
    const float* b1 = (const float*)d_in[4];
    const float* W2 = (const float*)d_in[5];
    const float* b2 = (const float*)d_in[6];
    float* out = (float*)d_out;

    char* ws = (char*)d_ws;
    unsigned short* x_bf  = (unsigned short*)(ws);                 // 8388608
    unsigned short* W1t   = (unsigned short*)(ws + 8388608);       // 33554432
    unsigned short* W2t   = (unsigned short*)(ws + 41943040);      // 33554432
    unsigned short* hbuf  = (unsigned short*)(ws + 75497472);      // 33554432
    int*   topk_e     = (int*)(ws + 109051904);
    float* topk_s     = (float*)(ws + 109084672);
    int*   token_list = (int*)(ws + 109117440);
    float* score_list = (float*)(ws + 109150208);
    int*   meta       = (int*)(ws + 109182976);   // meta[0..240] tiles; DO NOT touch past [240]

    hipMemsetAsync(d_out, 0, (size_t)TOKENS * DDIM * sizeof(float), stream);

    router_kernel<<<TOKENS / 4, 256, 0, stream>>>(x, Wr, br, x_bf, topk_e, topk_s);
    build_lists_kernel<<<1, 1024, 0, stream>>>(topk_e, topk_s, token_list, score_list, meta);
    transpose_cvt_kernel<<<dim3(512, 16), 256, 0, stream>>>(W1, W2, W1t, W2t);
    expert_gemm<DDIM, DDIM, HDIM, false><<<dim3(40, HDIM / 256, 1), 1024, 0, stream>>>(
        x_bf, W1t, b1, hbuf, nullptr, token_list, score_list, meta);
    expert_gemm<HDIM, HDIM / 2, DDIM, true><<<dim3(40, DDIM / 256, 2), 1024, 0, stream>>>(
        hbuf, W2t, b2, nullptr, out, token_list, score_list, meta);
}

// Round 7
// 387.467 us; speedup vs baseline: 2.5841x; 1.0562x over previous
//
#include <hip/hip_runtime.h>
#include <hip/hip_bf16.h>

#define TOKENS 4096
#define DDIM 1024
#define HDIM 2048
#define NEXP 8
#define NASSIGN 8192
#define TILE_M 128
#define MAX_TILES 80

typedef __attribute__((ext_vector_type(8))) __bf16 bf16x8;
typedef __attribute__((ext_vector_type(4))) float f32x4;
typedef __attribute__((ext_vector_type(4))) unsigned short u16x4;

__device__ __forceinline__ unsigned short f2bf(float f) {
    unsigned int u = __builtin_bit_cast(unsigned int, f);
    u += 0x7fffu + ((u >> 16) & 1u);
    return (unsigned short)(u >> 16);
}

// ---------------- router: logits = x @ Wr + br, top-2 + softmax; also x->bf16 ----------------
__global__ __launch_bounds__(256) void router_kernel(
    const float* __restrict__ x, const float* __restrict__ Wr, const float* __restrict__ br,
    unsigned short* __restrict__ x_bf, int* __restrict__ topk_e, float* __restrict__ topk_s)
{
    const int t = blockIdx.x * 4 + (threadIdx.x >> 6);
    const int lane = threadIdx.x & 63;
    const float* xr = x + (long)t * DDIM;
    unsigned short* xo = x_bf + (long)t * DDIM;
    float acc[8] = {0.f,0.f,0.f,0.f,0.f,0.f,0.f,0.f};
    for (int it = 0; it < DDIM / 64; ++it) {
        const int d = it * 64 + lane;
        const float xv = xr[d];
        xo[d] = f2bf(xv);
        const float4 w0 = *(const float4*)(Wr + d * 8);
        const float4 w1 = *(const float4*)(Wr + d * 8 + 4);
        acc[0] += xv * w0.x; acc[1] += xv * w0.y; acc[2] += xv * w0.z; acc[3] += xv * w0.w;
        acc[4] += xv * w1.x; acc[5] += xv * w1.y; acc[6] += xv * w1.z; acc[7] += xv * w1.w;
    }
#pragma unroll
    for (int e = 0; e < 8; ++e) {
        float v = acc[e];
        for (int off = 32; off > 0; off >>= 1) v += __shfl_down(v, off, 64);
        acc[e] = v;
    }
    if (lane == 0) {
        float lg[8];
#pragma unroll
        for (int e = 0; e < 8; ++e) lg[e] = acc[e] + br[e];
        int i0 = 0; float v0 = lg[0];
#pragma unroll
        for (int e = 1; e < 8; ++e) if (lg[e] > v0) { v0 = lg[e]; i0 = e; }
        int i1 = -1; float v1 = -3.4e38f;
#pragma unroll
        for (int e = 0; e < 8; ++e) if (e != i0 && lg[e] > v1) { v1 = lg[e]; i1 = e; }
        const float e1 = expf(v1 - v0);
        const float inv = 1.f / (1.f + e1);
        topk_e[t * 2]     = i0; topk_s[t * 2]     = inv;
        topk_e[t * 2 + 1] = i1; topk_s[t * 2 + 1] = e1 * inv;
    }
}

// ---------------- bucketing: counts -> scan -> scatter + tile map (128-row tiles) ----------------
__global__ __launch_bounds__(1024) void build_lists_kernel(
    const int* __restrict__ topk_e, const float* __restrict__ topk_s,
    int* __restrict__ token_list, float* __restrict__ score_list, int* __restrict__ meta)
{
    __shared__ int cnt[NEXP];
    __shared__ int base[NEXP];
    __shared__ int cur[NEXP];
    const int tid = threadIdx.x;
    if (tid < NEXP) cnt[tid] = 0;
    __syncthreads();
    for (int i = tid; i < NASSIGN; i += 1024) atomicAdd(&cnt[topk_e[i]], 1);
    __syncthreads();
    if (tid == 0) {
        int accu = 0;
        for (int e = 0; e < NEXP; ++e) { base[e] = accu; cur[e] = accu; accu += cnt[e]; }
        int ntile = 0;
        for (int e = 0; e < NEXP; ++e) {
            const int c = cnt[e];
            for (int r = 0; r * TILE_M < c; ++r) {
                meta[1 + ntile] = e;
                meta[1 + MAX_TILES + ntile] = base[e] + r * TILE_M;
                meta[1 + 2 * MAX_TILES + ntile] = (c - r * TILE_M) < TILE_M ? (c - r * TILE_M) : TILE_M;
                ++ntile;
            }
        }
        meta[0] = ntile;
    }
    __syncthreads();
    for (int i = tid; i < NASSIGN; i += 1024) {
        const int e = topk_e[i];
        const int slot = atomicAdd(&cur[e], 1);
        token_list[slot] = i >> 1;
        score_list[slot] = topk_s[i];
    }
}

// ---------------- W1 [E][D][H] + W2 [E][H][D] fp32 -> [E][N][K] bf16, one launch ----------------
// (No memoization: rounds 2/3 died from touching memory past meta[240] —
// workspace is sized to the original layout. Do NOT exceed it.)
__global__ __launch_bounds__(256) void transpose_cvt_kernel(
    const float* __restrict__ W1, const float* __restrict__ W2,
    unsigned short* __restrict__ W1t, unsigned short* __restrict__ W2t)
{
    __shared__ unsigned short tile[64 * 68];
    const int z = blockIdx.y;           // 0..7 -> W1 experts, 8..15 -> W2 experts
    const bool is1 = z < 8;
    const int e = is1 ? z : z - 8;
    const int K = is1 ? DDIM : HDIM;
    const int N = is1 ? HDIM : DDIM;
    const float* src = (is1 ? W1 : W2) + (long)e * K * N;
    unsigned short* dst = (is1 ? W1t : W2t) + (long)e * K * N;
    const int ktiles = K >> 6;
    const int k0 = (blockIdx.x % ktiles) * 64;
    const int n0 = (blockIdx.x / ktiles) * 64;
    const int r0 = threadIdx.x >> 4;
    const int c4 = (threadIdx.x & 15) * 4;
#pragma unroll
    for (int i = 0; i < 4; ++i) {
        const int r = r0 + i * 16;       // k-row within tile
        const float4 v = *(const float4*)(src + (long)(k0 + r) * N + n0 + c4);
        tile[(c4 + 0) * 68 + r] = f2bf(v.x);
        tile[(c4 + 1) * 68 + r] = f2bf(v.y);
        tile[(c4 + 2) * 68 + r] = f2bf(v.z);
        tile[(c4 + 3) * 68 + r] = f2bf(v.w);
    }
    __syncthreads();
#pragma unroll
    for (int i = 0; i < 4; ++i) {
        const int rn = r0 + i * 16;      // n-row within tile
        u16x4 o;
        o.x = tile[rn * 68 + c4 + 0];
        o.y = tile[rn * 68 + c4 + 1];
        o.z = tile[rn * 68 + c4 + 2];
        o.w = tile[rn * 68 + c4 + 3];
        *(u16x4*)(dst + (long)(n0 + rn) * K + k0 + c4) = o;
    }
}

// ---------------- grouped expert GEMM: 128x256 tile, BK=64, 8 waves, SINGLE-buffer ----------------
// Round 7 model (from rounds 0/4/6): GEMM time ~= staged_bytes / 6.2 TB/s once
// >= 2 blocks/CU are resident (round-0 G2: 528 blocks ~ 2/CU hit 6.05 TB/s);
// at 1 block/CU the single-buffer drain serializes and rate collapses to
// ~1.9 TB/s (round 6).  256^2 tiles can never reach 2 blocks/CU (16 wave-tiles
// -> 2 blocks needs <=64 regs/wave; acc alone is 64).  The reachable optimum
// is the ASYMMETRIC 128x256 tile: staged = A 138 + B 264 ~= 405 MB (vs 553 at
// 128^2), 512 thr / 8 waves (2M x 4N, 64x64 per wave), acc 64 + ~60 other
// regs ~= 124 unified -> 4 waves/SIMD -> 2 blocks/CU by regs AND by LDS
// (48 KB single-buffer).  G1: 66x8 = 528 blocks ~ 2.06/CU.  G2: split-K z=2
// -> 528 blocks.  Schedule + XOR-chunk swizzle = round 0's proven form.
// KDIM = row stride; KLOC = per-block K extent (bias only at z==0).
template<int KDIM, int KLOC, int NDIM, bool G2>
__global__ __launch_bounds__(512, 4) void expert_gemm(
    const unsigned short* __restrict__ Abase,
    const unsigned short* __restrict__ Bt,
    const float* __restrict__ bias,
    unsigned short* __restrict__ Hout,
    float* __restrict__ Out,
    const int* __restrict__ token_list,
    const float* __restrict__ score_list,
    const int* __restrict__ meta)
{
    const int nt = meta[0];
    // XCD-aware BIJECTIVE partition over tiles (gridDim.x = 80, xcd = bx&7).
    // nt <= 72, q <= 9, cnt_i <= 10 = gridDim.x/8; every tile covered once.
    const int xcd = blockIdx.x & 7;
    const int off = blockIdx.x >> 3;
    const int q = nt >> 3;
    const int r = nt & 7;
    const int cnt_i = q + (xcd < r ? 1 : 0);
    if (off >= cnt_i) return;
    const int t = xcd * q + (xcd < r ? xcd : r) + off;
    const int e = meta[1 + t];
    const int slot0 = meta[1 + MAX_TILES + t];
    const int rows_valid = meta[1 + 2 * MAX_TILES + t];
    const int n0 = blockIdx.y * 256;
    const int k_start = blockIdx.z * KLOC;

    __shared__ unsigned short As[128 * 64];   // 16 KB
    __shared__ unsigned short Bs[256 * 64];   // 32 KB -> 48 KB total, 2 blocks/CU

    const int tid = threadIdx.x;
    const int lane = tid & 63;
    const int w = tid >> 6;      // 8 waves: 2M x 4N, 64x64 output each
    const int wm = w >> 2;
    const int wn = w & 3;
    const int quad = lane >> 4;
    const int l15 = lane & 15;

    // Staging: A = 1024 16B-chunks (2/thread), B = 2048 (4/thread) per K-tile.
    // chunk = c*512 + tid; LDS slot = chunk*16B; row = chunk>>3; the global
    // k-chunk stored there is (chunk&7) XOR (row&7) -> on the read side,
    // slot (h*4+quad)^(l15&7) yields k-chunk h*4+quad, bank-conflict-free.
    const unsigned short* aptr[2];
    const unsigned short* bptr[4];
    int aoff[2], boff[4];
#pragma unroll
    for (int c = 0; c < 2; ++c) {
        const int chunk = c * 512 + tid;
        const int row = chunk >> 3;                 // 0..127
        const int kc = (chunk & 7) ^ (row & 7);
        const int rr = row < rows_valid ? row : rows_valid - 1;
        const long arow = G2 ? (long)(slot0 + rr) : (long)token_list[slot0 + rr];
        aptr[c] = Abase + arow * (long)KDIM + k_start + kc * 8;
        aoff[c] = (c * 512 + w * 64) * 8;           // wave-uniform base; HW adds lane*16B
    }
#pragma unroll
    for (int c = 0; c < 4; ++c) {
        const int chunk = c * 512 + tid;
        const int row = chunk >> 3;                 // 0..255
        const int kc = (chunk & 7) ^ (row & 7);
        bptr[c] = Bt + ((long)e * NDIM + n0 + row) * (long)KDIM + k_start + kc * 8;
        boff[c] = (c * 512 + w * 64) * 8;
    }

    f32x4 acc[4][4] = {};

#pragma unroll 1
    for (int k0 = 0; k0 < KLOC; k0 += 64) {
#pragma unroll
        for (int c = 0; c < 2; ++c) {
            __builtin_amdgcn_global_load_lds(
                (const __attribute__((address_space(1))) unsigned int*)aptr[c],
                (__attribute__((address_space(3))) unsigned int*)&As[aoff[c]], 16, 0, 0);
            aptr[c] += 64;
        }
#pragma unroll
        for (int c = 0; c < 4; ++c) {
            __builtin_amdgcn_global_load_lds(
                (const __attribute__((address_space(1))) unsigned int*)bptr[c],
                (__attribute__((address_space(3))) unsigned int*)&Bs[boff[c]], 16, 0, 0);
            bptr[c] += 64;
        }
        __syncthreads();

#pragma unroll
        for (int h = 0; h < 2; ++h) {
            bf16x8 af[4], bfr[4];
#pragma unroll
            for (int mi = 0; mi < 4; ++mi)
                af[mi] = *(const bf16x8*)&As[(wm * 64 + mi * 16 + l15) * 64 + ((h * 4 + quad) ^ (l15 & 7)) * 8];
#pragma unroll
            for (int ni = 0; ni < 4; ++ni)
                bfr[ni] = *(const bf16x8*)&Bs[(wn * 64 + ni * 16 + l15) * 64 + ((h * 4 + quad) ^ (l15 & 7)) * 8];
#pragma unroll
            for (int mi = 0; mi < 4; ++mi)
#pragma unroll
                for (int ni = 0; ni < 4; ++ni)
                    acc[mi][ni] = __builtin_amdgcn_mfma_f32_16x16x32_bf16(af[mi], bfr[ni], acc[mi][ni], 0, 0, 0);
        }
        __syncthreads();
    }

#pragma unroll
    for (int mi = 0; mi < 4; ++mi) {
#pragma unroll
        for (int ni = 0; ni < 4; ++ni) {
            const int col = n0 + wn * 64 + ni * 16 + l15;
#pragma unroll
            for (int rr = 0; rr < 4; ++rr) {
                const int row = wm * 64 + mi * 16 + quad * 4 + rr;
                if (row < rows_valid) {
                    float v = acc[mi][ni][rr];
                    if (!G2 || blockIdx.z == 0) v += bias[e * NDIM + col];
                    if (!G2) {
                        v = v > 0.f ? v : 0.f;
                        Hout[(long)(slot0 + row) * NDIM + col] = f2bf(v);
                    } else {
                        const int slot = slot0 + row;
                        const int tok = token_list[slot];
                        const float s = score_list[slot];
                        unsafeAtomicAdd(&Out[(long)tok * NDIM + col], s * v);
                    }
                }
            }
        }
    }
}

extern "C" void kernel_launch(void* const* d_in, const int* in_sizes, int n_in,
                              void* d_out, int out_size, void* d_ws, size_t ws_size,
                              hipStream_t stream)
{
    (void)in_sizes; (void)n_in; (void)out_size; (void)ws_size;
    const float* x  = (const float*)d_in[0];
    const float* Wr = (const float*)d_in[1];
    const float* br = (const float*)d_in[2];
    const float* W1 = (const float*)d_in[3];
    const float* b1 = (const float*)d_in[4];
    const float* W2 = (const float*)d_in[5];
    const float* b2 = (const float*)d_in[6];
    float* out = (float*)d_out;

    char* ws = (char*)d_ws;
    unsigned short* x_bf  = (unsigned short*)(ws);                 // 8388608
    unsigned short* W1t   = (unsigned short*)(ws + 8388608);       // 33554432
    unsigned short* W2t   = (unsigned short*)(ws + 41943040);      // 33554432
    unsigned short* hbuf  = (unsigned short*)(ws + 75497472);      // 33554432
    int*   topk_e     = (int*)(ws + 109051904);
    float* topk_s     = (float*)(ws + 109084672);
    int*   token_list = (int*)(ws + 109117440);
    float* score_list = (float*)(ws + 109150208);
    int*   meta       = (int*)(ws + 109182976);   // meta[0..240] tiles; DO NOT touch past [240]

    hipMemsetAsync(d_out, 0, (size_t)TOKENS * DDIM * sizeof(float), stream);

    router_kernel<<<TOKENS / 4, 256, 0, stream>>>(x, Wr, br, x_bf, topk_e, topk_s);
    build_lists_kernel<<<1, 1024, 0, stream>>>(topk_e, topk_s, token_list, score_list, meta);
    transpose_cvt_kernel<<<dim3(512, 16), 256, 0, stream>>>(W1, W2, W1t, W2t);
    expert_gemm<DDIM, DDIM, HDIM, false><<<dim3(80, HDIM / 256, 1), 512, 0, stream>>>(
        x_bf, W1t, b1, hbuf, nullptr, token_list, score_list, meta);
    expert_gemm<HDIM, HDIM / 2, DDIM, true><<<dim3(80, DDIM / 256, 2), 512, 0, stream>>>(
        hbuf, W2t, b2, nullptr, out, token_list, score_list, meta);
}

// Round 8
// 349.170 us; speedup vs baseline: 2.8675x; 1.1097x over previous
//
#include <hip/hip_runtime.h>
#include <hip/hip_bf16.h>

#define TOKENS 4096
#define DDIM 1024
#define HDIM 2048
#define NEXP 8
#define NASSIGN 8192
#define MAX_TILES 80

typedef __attribute__((ext_vector_type(8))) __bf16 bf16x8;
typedef __attribute__((ext_vector_type(4))) float f32x4;
typedef __attribute__((ext_vector_type(4))) unsigned short u16x4;
typedef __attribute__((ext_vector_type(8))) unsigned short u16x8;

__device__ __forceinline__ unsigned short f2bf(float f) {
    unsigned int u = __builtin_bit_cast(unsigned int, f);
    u += 0x7fffu + ((u >> 16) & 1u);
    return (unsigned short)(u >> 16);
}

// ---------------- router: logits = x @ Wr + br, top-2 + softmax; also x->bf16 ----------------
__global__ __launch_bounds__(256) void router_kernel(
    const float* __restrict__ x, const float* __restrict__ Wr, const float* __restrict__ br,
    unsigned short* __restrict__ x_bf, int* __restrict__ topk_e, float* __restrict__ topk_s)
{
    const int t = blockIdx.x * 4 + (threadIdx.x >> 6);
    const int lane = threadIdx.x & 63;
    const float* xr = x + (long)t * DDIM;
    unsigned short* xo = x_bf + (long)t * DDIM;
    float acc[8] = {0.f,0.f,0.f,0.f,0.f,0.f,0.f,0.f};
    for (int it = 0; it < DDIM / 64; ++it) {
        const int d = it * 64 + lane;
        const float xv = xr[d];
        xo[d] = f2bf(xv);
        const float4 w0 = *(const float4*)(Wr + d * 8);
        const float4 w1 = *(const float4*)(Wr + d * 8 + 4);
        acc[0] += xv * w0.x; acc[1] += xv * w0.y; acc[2] += xv * w0.z; acc[3] += xv * w0.w;
        acc[4] += xv * w1.x; acc[5] += xv * w1.y; acc[6] += xv * w1.z; acc[7] += xv * w1.w;
    }
#pragma unroll
    for (int e = 0; e < 8; ++e) {
        float v = acc[e];
        for (int off = 32; off > 0; off >>= 1) v += __shfl_down(v, off, 64);
        acc[e] = v;
    }
    if (lane == 0) {
        float lg[8];
#pragma unroll
        for (int e = 0; e < 8; ++e) lg[e] = acc[e] + br[e];
        int i0 = 0; float v0 = lg[0];
#pragma unroll
        for (int e = 1; e < 8; ++e) if (lg[e] > v0) { v0 = lg[e]; i0 = e; }
        int i1 = -1; float v1 = -3.4e38f;
#pragma unroll
        for (int e = 0; e < 8; ++e) if (e != i0 && lg[e] > v1) { v1 = lg[e]; i1 = e; }
        const float e1 = expf(v1 - v0);
        const float inv = 1.f / (1.f + e1);
        topk_e[t * 2]     = i0; topk_s[t * 2]     = inv;
        topk_e[t * 2 + 1] = i1; topk_s[t * 2 + 1] = e1 * inv;
    }
}

// ---------------- bucketing: per-wave replicated counters (16x less LDS-atomic contention) ----
// Round 8: old version was ONE block hammering 8 shared counters with 16K
// atomics (~20-30us of whole-machine serialization). Counters/cursors are now
// [16 waves][8 experts]; each wave's items hit only its own row. Bases and the
// 128-row tile table are computed in a short serial section. Output layout
// (token_list/score_list/meta) is IDENTICAL to round 0.
__global__ __launch_bounds__(1024) void build_lists_kernel(
    const int* __restrict__ topk_e, const float* __restrict__ topk_s,
    int* __restrict__ token_list, float* __restrict__ score_list, int* __restrict__ meta)
{
    __shared__ int cnt[16][NEXP];
    __shared__ int cur[16][NEXP];
    const int tid = threadIdx.x;
    const int wv = tid >> 6;
    if (tid < 16 * NEXP) ((int*)cnt)[tid] = 0;
    __syncthreads();
    for (int i = tid; i < NASSIGN; i += 1024) atomicAdd(&cnt[wv][topk_e[i]], 1);
    __syncthreads();
    if (tid == 0) {
        int tot[NEXP];
        for (int e = 0; e < NEXP; ++e) { int s = 0; for (int w = 0; w < 16; ++w) s += cnt[w][e]; tot[e] = s; }
        int accu = 0;
        for (int e = 0; e < NEXP; ++e) {
            int o = accu;
            for (int w = 0; w < 16; ++w) { cur[w][e] = o; o += cnt[w][e]; }
            accu += tot[e];
        }
        int ntile = 0; int b = 0;
        for (int e = 0; e < NEXP; ++e) {
            const int c = tot[e];
            for (int r = 0; r * 128 < c; ++r) {
                meta[1 + ntile] = e;
                meta[1 + MAX_TILES + ntile] = b + r * 128;
                meta[1 + 2 * MAX_TILES + ntile] = (c - r * 128) < 128 ? (c - r * 128) : 128;
                ++ntile;
            }
            b += c;
        }
        meta[0] = ntile;
    }
    __syncthreads();
    for (int i = tid; i < NASSIGN; i += 1024) {
        const int e = topk_e[i];
        const int slot = atomicAdd(&cur[wv][e], 1);
        token_list[slot] = i >> 1;
        score_list[slot] = topk_s[i];
    }
}

// ---------------- W1 [E][D][H] + W2 [E][H][D] fp32 -> [E][N][K] bf16 ----------------
// Round 8: 128k x 64n tiles, 16B LDS reads + 16B global stores (was 8B), half
// the blocks (4096). Same I/O contract. No memoization (rounds 2/3 died from
// touching memory past meta[240]; workspace is sized to the original layout).
__global__ __launch_bounds__(256) void transpose_cvt_kernel(
    const float* __restrict__ W1, const float* __restrict__ W2,
    unsigned short* __restrict__ W1t, unsigned short* __restrict__ W2t)
{
    __shared__ unsigned short tile[64 * 136];   // [n][k], k-stride 136 shorts (16B-aligned rows)
    const int z = blockIdx.y;           // 0..7 -> W1 experts, 8..15 -> W2 experts
    const bool is1 = z < 8;
    const int e = is1 ? z : z - 8;
    const int K = is1 ? DDIM : HDIM;
    const int N = is1 ? HDIM : DDIM;
    const float* src = (is1 ? W1 : W2) + (long)e * K * N;
    unsigned short* dst = (is1 ? W1t : W2t) + (long)e * K * N;
    const int ktiles = K >> 7;                       // 128-wide k tiles
    const int k0 = (blockIdx.x % ktiles) * 128;
    const int n0 = (blockIdx.x / ktiles) * 64;
    const int kr = threadIdx.x >> 4;
    const int c4 = (threadIdx.x & 15) * 4;
#pragma unroll
    for (int i = 0; i < 8; ++i) {
        const int r = kr + i * 16;       // k-row within tile (0..127)
        const float4 v = *(const float4*)(src + (long)(k0 + r) * N + n0 + c4);
        tile[(c4 + 0) * 136 + r] = f2bf(v.x);
        tile[(c4 + 1) * 136 + r] = f2bf(v.y);
        tile[(c4 + 2) * 136 + r] = f2bf(v.z);
        tile[(c4 + 3) * 136 + r] = f2bf(v.w);
    }
    __syncthreads();
    const int nr = threadIdx.x >> 4;
    const int c8 = (threadIdx.x & 15) * 8;
#pragma unroll
    for (int i = 0; i < 4; ++i) {
        const int n = nr + i * 16;       // n-row within tile (0..63)
        const u16x8 o = *(const u16x8*)&tile[n * 136 + c8];
        *(u16x8*)(dst + (long)(n0 + n) * K + k0 + c8) = o;
    }
}

// ---------------- grouped expert GEMM: round-0 form restored VERBATIM ----------------
// 128x128 tile, BK=64, 4 waves (2x2), SINGLE-buffer 32KB LDS, XOR-chunk swizzle.
// Lesson of rounds 1/4/6/7: this kernel's staging rate (6.2 TB/s chip-wide)
// comes from MANY SMALL INDEPENDENT barrier domains — 4-wave blocks at 2-4
// blocks/CU whose stage/drain/compute phases interleave ACROSS blocks. Every
// redesign (dbuf 64KB, 256^2 128KB, 1024-thr, 128x256) widened blocks and/or
// cut blocks/CU and collapsed the rate to 1.9-5 TB/s. Round-0 G2 at 2.06
// blocks/CU already ran the same 6.2 TB/s as G1 at 4.1 -> this config
// saturates what the vmcnt(0)-drain schedule can reach. Do not re-trade
// block-level TLP for in-block ILP; next GEMM attempt must be a different
// schedule class (8-phase counted-vmcnt), not geometry.
template<int KDIM, int NDIM, bool G2>
__global__ __launch_bounds__(256, 2) void expert_gemm(
    const unsigned short* __restrict__ Abase,
    const unsigned short* __restrict__ Bt,
    const float* __restrict__ bias,
    unsigned short* __restrict__ Hout,
    float* __restrict__ Out,
    const int* __restrict__ token_list,
    const float* __restrict__ score_list,
    const int* __restrict__ meta)
{
    const int nt = meta[0];
    // XCD-aware BIJECTIVE partition: XCD ~ bx%8 (gridDim.x=80, multiple of 8).
    const int xcd = blockIdx.x & 7;
    const int off = blockIdx.x >> 3;
    const int q = nt >> 3;
    const int r = nt & 7;
    const int cnt_i = q + (xcd < r ? 1 : 0);
    if (off >= cnt_i) return;
    const int t = xcd * q + (xcd < r ? xcd : r) + off;
    const int e = meta[1 + t];
    const int slot0 = meta[1 + MAX_TILES + t];
    const int rows_valid = meta[1 + 2 * MAX_TILES + t];
    const int n0 = blockIdx.y * 128;

    __shared__ unsigned short As[128 * 64];
    __shared__ unsigned short Bs[128 * 64];

    const int tid = threadIdx.x;
    const int lane = tid & 63;
    const int w = tid >> 6;
    const int wm = w & 1;
    const int wn = w >> 1;
    const int quad = lane >> 4;
    const int l15 = lane & 15;

    // Staging: 1024 16B-chunks per matrix per K-tile; chunk = c*256 + tid.
    // LDS slot for chunk = row*64 + (chunk&7)*8 shorts; the global k-chunk that
    // lands there is (chunk&7) XOR (row&7)  -> bank-conflict-free b128 reads.
    const unsigned short* aptr[4];
    const unsigned short* bptr[4];
    unsigned short* lA[4];
    unsigned short* lB[4];
#pragma unroll
    for (int c = 0; c < 4; ++c) {
        const int chunk = c * 256 + tid;
        const int row = chunk >> 3;
        const int kc = (chunk & 7) ^ (row & 7);
        const int rr = row < rows_valid ? row : rows_valid - 1;
        const long arow = G2 ? (long)(slot0 + rr) : (long)token_list[slot0 + rr];
        aptr[c] = Abase + arow * (long)KDIM + kc * 8;
        bptr[c] = Bt + ((long)e * NDIM + n0 + row) * (long)KDIM + kc * 8;
        lA[c] = &As[(c * 256 + w * 64) * 8];
        lB[c] = &Bs[(c * 256 + w * 64) * 8];
    }

    f32x4 acc[4][4] = {};

#pragma unroll 1
    for (int k0 = 0; k0 < KDIM; k0 += 64) {
#pragma unroll
        for (int c = 0; c < 4; ++c) {
            __builtin_amdgcn_global_load_lds(
                (const __attribute__((address_space(1))) unsigned int*)aptr[c],
                (__attribute__((address_space(3))) unsigned int*)lA[c], 16, 0, 0);
            aptr[c] += 64;
        }
#pragma unroll
        for (int c = 0; c < 4; ++c) {
            __builtin_amdgcn_global_load_lds(
                (const __attribute__((address_space(1))) unsigned int*)bptr[c],
                (__attribute__((address_space(3))) unsigned int*)lB[c], 16, 0, 0);
            bptr[c] += 64;
        }
        __syncthreads();

#pragma unroll
        for (int h = 0; h < 2; ++h) {
            bf16x8 af[4], bfr[4];
#pragma unroll
            for (int mi = 0; mi < 4; ++mi)
                af[mi] = *(const bf16x8*)&As[(wm * 64 + mi * 16 + l15) * 64 + ((h * 4 + quad) ^ (l15 & 7)) * 8];
#pragma unroll
            for (int ni = 0; ni < 4; ++ni)
                bfr[ni] = *(const bf16x8*)&Bs[(wn * 64 + ni * 16 + l15) * 64 + ((h * 4 + quad) ^ (l15 & 7)) * 8];
#pragma unroll
            for (int mi = 0; mi < 4; ++mi)
#pragma unroll
                for (int ni = 0; ni < 4; ++ni)
                    acc[mi][ni] = __builtin_amdgcn_mfma_f32_16x16x32_bf16(af[mi], bfr[ni], acc[mi][ni], 0, 0, 0);
        }
        __syncthreads();
    }

#pragma unroll
    for (int mi = 0; mi < 4; ++mi) {
#pragma unroll
        for (int ni = 0; ni < 4; ++ni) {
            const int col = n0 + wn * 64 + ni * 16 + l15;
#pragma unroll
            for (int rr = 0; rr < 4; ++rr) {
                const int row = wm * 64 + mi * 16 + quad * 4 + rr;
                if (row < rows_valid) {
                    float v = acc[mi][ni][rr] + bias[e * NDIM + col];
                    if (!G2) {
                        v = v > 0.f ? v : 0.f;
                        Hout[(long)(slot0 + row) * NDIM + col] = f2bf(v);
                    } else {
                        const int slot = slot0 + row;
                        const int tok = token_list[slot];
                        const float s = score_list[slot];
                        unsafeAtomicAdd(&Out[(long)tok * NDIM + col], s * v);
                    }
                }
            }
        }
    }
}

extern "C" void kernel_launch(void* const* d_in, const int* in_sizes, int n_in,
                              void* d_out, int out_size, void* d_ws, size_t ws_size,
                              hipStream_t stream)
{
    (void)in_sizes; (void)n_in; (void)out_size; (void)ws_size;
    const float* x  = (const float*)d_in[0];
    const float* Wr = (const float*)d_in[1];
    const float* br = (const float*)d_in[2];
    const float* W1 = (const float*)d_in[3];
    const float* b1 = (const float*)d_in[4];
    const float* W2 = (const float*)d_in[5];
    const float* b2 = (const float*)d_in[6];
    float* out = (float*)d_out;

    char* ws = (char*)d_ws;
    unsigned short* x_bf  = (unsigned short*)(ws);                 // 8388608
    unsigned short* W1t   = (unsigned short*)(ws + 8388608);       // 33554432
    unsigned short* W2t   = (unsigned short*)(ws + 41943040);      // 33554432
    unsigned short* hbuf  = (unsigned short*)(ws + 75497472);      // 33554432
    int*   topk_e     = (int*)(ws + 109051904);
    float* topk_s     = (float*)(ws + 109084672);
    int*   token_list = (int*)(ws + 109117440);
    float* score_list = (float*)(ws + 109150208);
    int*   meta       = (int*)(ws + 109182976);   // meta[0..240] tiles; DO NOT touch past [240]

    hipMemsetAsync(d_out, 0, (size_t)TOKENS * DDIM * sizeof(float), stream);

    router_kernel<<<TOKENS / 4, 256, 0, stream>>>(x, Wr, br, x_bf, topk_e, topk_s);
    build_lists_kernel<<<1, 1024, 0, stream>>>(topk_e, topk_s, token_list, score_list, meta);
    transpose_cvt_kernel<<<dim3(256, 16), 256, 0, stream>>>(W1, W2, W1t, W2t);
    expert_gemm<DDIM, HDIM, false><<<dim3(MAX_TILES, HDIM / 128), 256, 0, stream>>>(
        x_bf, W1t, b1, hbuf, nullptr, token_list, score_list, meta);
    expert_gemm<HDIM, DDIM, true><<<dim3(MAX_TILES, DDIM / 128), 256, 0, stream>>>(
        hbuf, W2t, b2, nullptr, out, token_list, score_list, meta);
}